// Round 8
// baseline (92.950 us; speedup 1.0000x reference)
//
#include <hip/hip_runtime.h>
#include <math.h>

// Problem constants (fixed by setup_inputs)
#define B_   16
#define C_   512
#define CR_  128
#define N_   4096
#define N4_  (N_ / 4)          // 1024 float4 per row
#define TN   32                // tile width in floats (128B per row-chunk)
#define TN4  (TN / 4)          // 8 float4 per tile-row
#define NTB  (N_ / TN)         // 128 tile-blocks per batch -> 2048 blocks

static constexpr float BN_EPS_F = 1e-5f;

typedef float vfloat4 __attribute__((ext_vector_type(4)));

// ---------------------------------------------------------------------------
// K1f: fused colsum + att partials.  ONE pass over x, one tile per block.
// Block (ntb, b), thread t: g=t>>3 (row-group 0..31), i=t&7 (f4 col 0..7).
// Load 16 rows (c=st*32+g) x 1 f4 -> v[16]; LDS-reduce column sums over g ->
// s_tile (complete s for these 32 n's: all 512 channels in tile); dot each
// v[st] with s, 8-lane shfl reduce over i, lane i==0 writes att_part.
// ---------------------------------------------------------------------------
__global__ __launch_bounds__(256) void k1f_att(
        const float* __restrict__ x,
        float* __restrict__ att_part) {
    const int ntb = blockIdx.x;          // [0, NTB)
    const int b   = blockIdx.y;          // [0, 16)
    const int t   = threadIdx.x;
    const int g   = t >> 3;              // [0, 32)
    const int i   = t & 7;               // [0, 8)

    __shared__ vfloat4 s_red[32][8];
    __shared__ vfloat4 s_tile4[8];

    const vfloat4* base = (const vfloat4*)x + (size_t)b * C_ * N4_ + (size_t)ntb * TN4;
    vfloat4 v[16];
    vfloat4 sacc = {0.f, 0.f, 0.f, 0.f};
#pragma unroll
    for (int st = 0; st < 16; ++st) {
        v[st] = base[(size_t)(st * 32 + g) * N4_ + i];
        sacc += v[st];
    }
    s_red[g][i] = sacc;
    __syncthreads();
    if (t < 8) {
        vfloat4 acc = {0.f, 0.f, 0.f, 0.f};
#pragma unroll
        for (int g2 = 0; g2 < 32; ++g2)
            acc += s_red[g2][t];
        s_tile4[t] = acc;
    }
    __syncthreads();
    const vfloat4 sv = s_tile4[i];

    float* dst = att_part + ((size_t)ntb * B_ + b) * C_;
#pragma unroll
    for (int st = 0; st < 16; ++st) {
        float d = v[st].x * sv.x + v[st].y * sv.y
                + v[st].z * sv.z + v[st].w * sv.w;
        d += __shfl_xor(d, 1, 64);
        d += __shfl_xor(d, 2, 64);
        d += __shfl_xor(d, 4, 64);       // sum over i within 8-lane group
        if (i == 0) dst[st * 32 + g] = d;
    }
}

// ---------------------------------------------------------------------------
// K3f: att-partial reduce + dense1 + BN + ReLU + dense2 + sigmoid.
// One block per batch b (16 blocks, 256 threads).
// ---------------------------------------------------------------------------
__global__ void k3f(const float* __restrict__ att_part,
                    const float* __restrict__ W1,
                    const float* __restrict__ gamma,
                    const float* __restrict__ beta,
                    const float* __restrict__ rmean,
                    const float* __restrict__ rvar,
                    const float* __restrict__ W2,
                    float* __restrict__ a) {
    __shared__ float att_s[C_];
    __shared__ float h_s[CR_];
    const int b = blockIdx.x;
    const int t = threadIdx.x;

    {
        float a0 = 0.f, a1 = 0.f;
#pragma unroll 8
        for (int nb = 0; nb < NTB; ++nb) {
            const float* p = att_part + ((size_t)nb * B_ + b) * C_;
            a0 += p[t];
            a1 += p[t + 256];
        }
        att_s[t]       = a0;
        att_s[t + 256] = a1;
    }
    __syncthreads();

    if (t < CR_) {
        const float* w = W1 + (size_t)t * C_;
        float a0 = 0.f, a1 = 0.f, a2 = 0.f, a3 = 0.f;
#pragma unroll 4
        for (int c = 0; c < C_; c += 4) {
            a0 += w[c + 0] * att_s[c + 0];
            a1 += w[c + 1] * att_s[c + 1];
            a2 += w[c + 2] * att_s[c + 2];
            a3 += w[c + 3] * att_s[c + 3];
        }
        float acc = (a0 + a1) + (a2 + a3);
        float vv = gamma[t] * (acc - rmean[t]) * rsqrtf(rvar[t] + BN_EPS_F) + beta[t];
        h_s[t] = fmaxf(vv, 0.f);
    }
    __syncthreads();
#pragma unroll
    for (int j0 = 0; j0 < C_; j0 += 256) {
        const int j = j0 + t;
        const float* w = W2 + (size_t)j * CR_;
        float a0 = 0.f, a1 = 0.f, a2 = 0.f, a3 = 0.f;
#pragma unroll 4
        for (int k = 0; k < CR_; k += 4) {
            a0 += w[k + 0] * h_s[k + 0];
            a1 += w[k + 1] * h_s[k + 1];
            a2 += w[k + 2] * h_s[k + 2];
            a3 += w[k + 3] * h_s[k + 3];
        }
        float acc = (a0 + a1) + (a2 + a3);
        a[(size_t)b * C_ + j] = 1.f / (1.f + expf(-acc));
    }
}

// ---------------------------------------------------------------------------
// K4: out[b,c,n] = x[b,c,n] * a[b,c].  Block-per-row: a is block-uniform,
// accesses contiguous, NT stores keep out-writes from evicting x in L3.
// ---------------------------------------------------------------------------
__global__ __launch_bounds__(256) void k4_scale(
        const float* __restrict__ x,
        const float* __restrict__ a,
        float* __restrict__ out) {
    const int row = blockIdx.x;          // [0, B*C)
    const float av = a[row];
    const vfloat4* xr = (const vfloat4*)x + (size_t)row * N4_;
    vfloat4* orow     = (vfloat4*)out     + (size_t)row * N4_;
#pragma unroll
    for (int it = 0; it < N4_ / 256; ++it) {   // 4 iters
        const int idx = it * 256 + threadIdx.x;
        vfloat4 ov = xr[idx] * av;
        __builtin_nontemporal_store(ov, &orow[idx]);
    }
}

// ---------------------------------------------------------------------------
extern "C" void kernel_launch(void* const* d_in, const int* in_sizes, int n_in,
                              void* d_out, int out_size, void* d_ws, size_t ws_size,
                              hipStream_t stream) {
    const float* x     = (const float*)d_in[0];
    const float* W1    = (const float*)d_in[1];
    const float* gamma = (const float*)d_in[2];
    const float* beta  = (const float*)d_in[3];
    const float* rmean = (const float*)d_in[4];
    const float* rvar  = (const float*)d_in[5];
    const float* W2    = (const float*)d_in[6];
    float* out = (float*)d_out;

    // Workspace (floats): att_part 128*16*512 = 1M floats (4 MiB), a 8192
    float* ws       = (float*)d_ws;
    float* att_part = ws;
    float* a        = att_part + (size_t)NTB * B_ * C_;

    k1f_att<<<dim3(NTB, B_), 256, 0, stream>>>(x, att_part);
    k3f<<<dim3(B_), 256, 0, stream>>>(att_part, W1, gamma, beta, rmean, rvar, W2, a);
    k4_scale<<<dim3(B_ * C_), 256, 0, stream>>>(x, a, out);
}